// Round 1
// 9297.630 us; speedup vs baseline: 1.0987x; 1.0987x over previous
//
#include <hip/hip_runtime.h>
#include <stdint.h>

#define T_SEQ 1024
#define BATCH 32
#define HID   512
#define RING  32     // inter-stage ring depth (power of 2)

typedef unsigned short u16;
typedef unsigned long long u64;
typedef short bf16x8 __attribute__((ext_vector_type(8)));
typedef float f32x4  __attribute__((ext_vector_type(4)));
typedef unsigned int u32x4 __attribute__((ext_vector_type(4)));

__device__ __forceinline__ float bf2f(u16 u) {
  union { unsigned u; float f; } v; v.u = ((unsigned)u) << 16; return v.f;
}
__device__ __forceinline__ u16 f2bf(float f) {
  union { float f; unsigned u; } v; v.f = f;
  unsigned r = v.u + 0x7fffu + ((v.u >> 16) & 1u);   // RNE
  return (u16)(r >> 16);
}
__device__ __forceinline__ float sigf(float x) { return 1.0f / (1.0f + __expf(-x)); }
__device__ __forceinline__ float tanh_fast(float x) { return 2.0f * sigf(2.0f * x) - 1.0f; }

// Device-scope coherent publish + flags (atomics: correctness of the protocol).
__device__ __forceinline__ void st_dev(u64* p, u64 v) {
  __hip_atomic_store(p, v, __ATOMIC_RELAXED, __HIP_MEMORY_SCOPE_AGENT);
}
__device__ __forceinline__ int ld_flag(const int* p) {
  return __hip_atomic_load(p, __ATOMIC_RELAXED, __HIP_MEMORY_SCOPE_AGENT);
}

// Coherent 16B data load/store: sc0 sc1 bypass L1 + per-XCD L2 (serve from the
// cross-XCD coherence point) WITHOUT atomic-codegen per-load serialization.
// Hazard tracking is manual: caller must s_waitcnt + sched_barrier before use.
#define GLD16(dst, p, OFS) \
  asm volatile("global_load_dwordx4 %0, %1, off offset:" OFS " sc0 sc1" \
               : "=v"(dst) : "v"(p) : "memory")
#define GST16(p, val, OFS) \
  asm volatile("global_store_dwordx4 %0, %1, off offset:" OFS " sc0 sc1" \
               :: "v"(p), "v"(val) : "memory")

// 16 named 16B registers (64 VGPRs) so SROA keeps everything in registers.
struct Frag {
  u32x4 d0,d1,d2,d3,d4,d5,d6,d7,d8,d9,d10,d11,d12,d13,d14,d15;
};

// Issue a full 16-row x K=512 A-fragment fetch: 16 back-to-back coherent
// dwordx4 loads off one base pointer (offsets fit the 13-bit imm).
__device__ __forceinline__ void issue_frag(const u16* p, Frag& f) {
  GLD16(f.d0,  p, "0");   GLD16(f.d1,  p, "64");
  GLD16(f.d2,  p, "128"); GLD16(f.d3,  p, "192");
  GLD16(f.d4,  p, "256"); GLD16(f.d5,  p, "320");
  GLD16(f.d6,  p, "384"); GLD16(f.d7,  p, "448");
  GLD16(f.d8,  p, "512"); GLD16(f.d9,  p, "576");
  GLD16(f.d10, p, "640"); GLD16(f.d11, p, "704");
  GLD16(f.d12, p, "768"); GLD16(f.d13, p, "832");
  GLD16(f.d14, p, "896"); GLD16(f.d15, p, "960");
}

// K=512 16x16x32 MFMA chain over a pre-loaded fragment. 4 accumulators to
// keep the dependent-MFMA chains short.
__device__ __forceinline__ f32x4 frag_compute(const Frag& f, const u16 (*w)[520],
                                              int wrow, int kq) {
  f32x4 z = {0.f,0.f,0.f,0.f};
  f32x4 a[4] = {z, z, z, z};
#define FSTEP(ii, dd) { union { u32x4 q; bf16x8 v; } c; c.q = f.dd; \
  bf16x8 bv = *reinterpret_cast<const bf16x8*>(&w[wrow][kq + ii * 32]); \
  a[ii & 3] = __builtin_amdgcn_mfma_f32_16x16x32_bf16(c.v, bv, a[ii & 3], 0, 0, 0); }
  FSTEP(0,d0)   FSTEP(1,d1)   FSTEP(2,d2)   FSTEP(3,d3)
  FSTEP(4,d4)   FSTEP(5,d5)   FSTEP(6,d6)   FSTEP(7,d7)
  FSTEP(8,d8)   FSTEP(9,d9)   FSTEP(10,d10) FSTEP(11,d11)
  FSTEP(12,d12) FSTEP(13,d13) FSTEP(14,d14) FSTEP(15,d15)
#undef FSTEP
  return (a[0] + a[1]) + (a[2] + a[3]);
}

// ---------------- cast fp32 -> bf16 ----------------
__global__ __launch_bounds__(256) void cast_f32_bf16(const float* __restrict__ in,
                                                     u16* __restrict__ out, int n) {
  int i = (blockIdx.x * 256 + threadIdx.x) * 8;
  if (i + 7 < n) {
    float4 v0 = *reinterpret_cast<const float4*>(in + i);
    float4 v1 = *reinterpret_cast<const float4*>(in + i + 4);
    uint4 o;
    o.x = (unsigned)f2bf(v0.x) | ((unsigned)f2bf(v0.y) << 16);
    o.y = (unsigned)f2bf(v0.z) | ((unsigned)f2bf(v0.w) << 16);
    o.z = (unsigned)f2bf(v1.x) | ((unsigned)f2bf(v1.y) << 16);
    o.w = (unsigned)f2bf(v1.z) | ((unsigned)f2bf(v1.w) << 16);
    *reinterpret_cast<uint4*>(out + i) = o;
  } else {
    for (; i < n; ++i) out[i] = f2bf(in[i]);
  }
}

// ---------------- LSTM input GEMM: out[t][b][k][g] = x @ w_ih^T + b_ih + b_hh ----------------
__global__ __launch_bounds__(256) void gemm_xg(
    const u16* __restrict__ A, const u16* __restrict__ W,
    const float* __restrict__ bias1, const float* __restrict__ bias2,
    u16* __restrict__ out, int N, int K, int strideB, int strideT)
{
  __shared__ u16 As[64][72];
  __shared__ u16 Bs[64][72];
  int tid  = threadIdx.x;
  int lane = tid & 63;
  int wave = tid >> 6;
  int m0 = blockIdx.x * 64;
  int n0 = blockIdx.y * 64;

  f32x4 zero = {0.f, 0.f, 0.f, 0.f};
  f32x4 acc[4] = {zero, zero, zero, zero};

  int srow = tid >> 2;
  int scol = (tid & 3) * 16;

  int m_s = m0 + srow;
  long arow = (long)(m_s & (BATCH - 1)) * strideB + (long)(m_s >> 5) * strideT;
  const u16* aptr = A + arow * K + scol;
  const u16* wptr = W + (long)(n0 + srow) * K + scol;

  for (int kk = 0; kk < K; kk += 64) {
    __syncthreads();
    uint4 a0 = *reinterpret_cast<const uint4*>(aptr + kk);
    uint4 a1 = *reinterpret_cast<const uint4*>(aptr + kk + 8);
    uint4 b0 = *reinterpret_cast<const uint4*>(wptr + kk);
    uint4 b1 = *reinterpret_cast<const uint4*>(wptr + kk + 8);
    *reinterpret_cast<uint4*>(&As[srow][scol])     = a0;
    *reinterpret_cast<uint4*>(&As[srow][scol + 8]) = a1;
    *reinterpret_cast<uint4*>(&Bs[srow][scol])     = b0;
    *reinterpret_cast<uint4*>(&Bs[srow][scol + 8]) = b1;
    __syncthreads();
    int am = wave * 16 + (lane & 15);
    int kq = (lane >> 4) * 8;
#pragma unroll
    for (int ks = 0; ks < 2; ++ks) {
      bf16x8 af = *reinterpret_cast<const bf16x8*>(&As[am][kq + ks * 32]);
#pragma unroll
      for (int nb = 0; nb < 4; ++nb) {
        bf16x8 bf = *reinterpret_cast<const bf16x8*>(&Bs[nb * 16 + (lane & 15)][kq + ks * 32]);
        acc[nb] = __builtin_amdgcn_mfma_f32_16x16x32_bf16(af, bf, acc[nb], 0, 0, 0);
      }
    }
  }
  int quad = lane >> 4;
#pragma unroll
  for (int nb = 0; nb < 4; ++nb) {
    int n = n0 + nb * 16 + (lane & 15);
    float bv = bias1[n] + (bias2 ? bias2[n] : 0.0f);
    int g = n >> 9, k = n & 511;
#pragma unroll
    for (int r = 0; r < 4; ++r) {
      int m = m0 + wave * 16 + quad * 4 + r;
      int t = m >> 5, b = m & (BATCH - 1);
      out[(((long)t * BATCH + b) * HID + k) * 4 + g] = f2bf(acc[nb][r] + bv);
    }
  }
}

// ---------------- persistent recurrent role (ROLE: 0=LSTM 1=GRU 2=RNN) ----------------
template <int ROLE>
__device__ void recur_role(
    int wg, const u16* __restrict__ xg, const u16* __restrict__ up,
    const u16* __restrict__ wih, const u16* __restrict__ whh,
    const float* __restrict__ bih, const float* __restrict__ bhh,
    u16* __restrict__ hist, const int* fl_up, int n_up, int* fl_own,
    const int* cons, int n_cons,
    u16 (*w_lds)[520], float (*gx)[33], float (*gh)[33], u16 (*hs)[8])
{
  constexpr int NG = (ROLE == 0) ? 4 : (ROLE == 1) ? 3 : 1;
  constexpr int NPAD = (ROLE == 2) ? 16 : 32;
  constexpr int XROWS = (ROLE > 0) ? NG * 8 : 0;   // x-weight rows staged
  constexpr int TOT = XROWS + NG * 8;
  constexpr int RH = (ROLE == 2) ? 2 : RING;
  int tid = threadIdx.x, lane = tid & 63, wave = tid >> 6;
  int hbase = wg * 8;

  // stage weights compactly: rows [0,XROWS) = w_ih slice, [XROWS,TOT) = w_hh slice
  for (int idx = tid; idx < TOT * 64; idx += 256) {
    int row = idx >> 6, chunk = idx & 63;
    int n = (row < XROWS) ? row : (row - XROWS);
    const u16* src = (row < XROWS) ? wih : whh;
    int g = n >> 3, dd = n & 7;
    uint4 v = *reinterpret_cast<const uint4*>(src + ((long)(g * 512 + hbase + dd)) * 512 + chunk * 8);
    *reinterpret_cast<uint4*>(&w_lds[row][chunk * 8]) = v;
  }
  __syncthreads();

  int mt = wave & 1, nt = wave >> 1;
  bool mact = (nt * 16) < NPAD;
  int colw = nt * 16 + (lane & 15);
  int wr = (colw < NG * 8) ? colw : (NG * 8 - 1);   // clamped B row (cols>=NG*8 unused)
  int arow = mt * 16 + (lane & 15);
  int kq = (lane >> 4) * 8;
  float bxw = 0.f, bhw = 0.f;
  if (colw < NG * 8) {
    int g = colw >> 3, dd = colw & 7;
    if constexpr (ROLE == 1) { bxw = bih[g * 512 + hbase + dd]; bhw = bhh[g * 512 + hbase + dd]; }
    if constexpr (ROLE == 2) { bxw = bih[hbase + dd] + bhh[hbase + dd]; }
    (void)g;
  }
  int b_c = tid >> 3, d_c = tid & 7;   // cell thread owns h[b_c][hbase+d_c]
  float c_st = 0.f, h_st = 0.f;

  for (int t = 0; t < T_SEQ; ++t) {
    u64 xq = 0;
    if constexpr (ROLE == 0)
      xq = *reinterpret_cast<const u64*>(xg + (((long)t * BATCH + b_c) * HID + hbase + d_c) * 4);

    f32x4 aX = {0.f,0.f,0.f,0.f}, aH = {0.f,0.f,0.f,0.f};
    if (mact) {
      Frag fX, fH;
      // --- polls FIRST (a poll load inside the vmcnt FIFO would drain our
      // data loads), then issue all data loads back-to-back, counted waits. ---
      if constexpr (ROLE > 0) {
        int tgt = t + 1;
        while (true) {
          int f = tgt;
          if (lane < n_up) f = ld_flag(&fl_up[lane]);
          if (__all(f >= tgt)) break;
          __builtin_amdgcn_s_sleep(1);
        }
      }
      if (t > 0) {
        while (true) {
          int f = ld_flag(&fl_own[lane]);
          if (__all(f >= t)) break;
          __builtin_amdgcn_s_sleep(1);
        }
      }
      __asm__ volatile("" ::: "memory");
      if constexpr (ROLE > 0)
        issue_frag(up + ((long)(t & (RING - 1)) * BATCH + arow) * HID + kq, fX);
      if (t > 0)
        issue_frag(hist + ((long)((t - 1) & (RH - 1)) * BATCH + arow) * HID + kq, fH);

      if constexpr (ROLE > 0) {
        // fX is the 16 oldest in-flight loads: vmcnt(16) releases them while
        // fH is still flying -> aX MFMAs overlap the aH load latency.
        if (t > 0) asm volatile("s_waitcnt vmcnt(16)" ::: "memory");
        else       asm volatile("s_waitcnt vmcnt(0)"  ::: "memory");
        __builtin_amdgcn_sched_barrier(0);
        aX = frag_compute(fX, w_lds, wr, kq);
      }
      if (t > 0) {
        asm volatile("s_waitcnt vmcnt(0)" ::: "memory");
        __builtin_amdgcn_sched_barrier(0);
        aH = frag_compute(fH, w_lds + XROWS, wr, kq);
      }
      int quad = lane >> 4;
#pragma unroll
      for (int r = 0; r < 4; ++r) {
        int row = mt * 16 + quad * 4 + r;
        gx[row][colw] = aX[r] + bxw;
        gh[row][colw] = aH[r] + bhw;
      }
    }
    __syncthreads();

    float hnew;
    if constexpr (ROLE == 0) {
      float xv0 = bf2f((u16)(xq));
      float xv1 = bf2f((u16)(xq >> 16));
      float xv2 = bf2f((u16)(xq >> 32));
      float xv3 = bf2f((u16)(xq >> 48));
      float h0 = gh[b_c][0 * 8 + d_c];
      float h1 = gh[b_c][1 * 8 + d_c];
      float h2 = gh[b_c][2 * 8 + d_c];
      float h3 = gh[b_c][3 * 8 + d_c];
      float ig = sigf(xv0 + h0), fg = sigf(xv1 + h1);
      float gg = tanh_fast(xv2 + h2), og = sigf(xv3 + h3);
      c_st = fg * c_st + ig * gg;
      hnew = og * tanh_fast(c_st);
    } else if constexpr (ROLE == 1) {
      float xr_ = gx[b_c][0 * 8 + d_c], xz = gx[b_c][1 * 8 + d_c], xn = gx[b_c][2 * 8 + d_c];
      float hr  = gh[b_c][0 * 8 + d_c], hz = gh[b_c][1 * 8 + d_c], hn = gh[b_c][2 * 8 + d_c];
      float r = sigf(xr_ + hr), z = sigf(xz + hz);
      float n = tanh_fast(xn + r * hn);
      hnew = (1.f - z) * n + z * h_st;
      h_st = hnew;
    } else {
      hnew = tanh_fast(gx[b_c][d_c] + gh[b_c][d_c]);
    }
    hs[b_c][d_c] = f2bf(hnew);
    __syncthreads();

    if (wave == 0) {
      // back-pressure: downstream must have consumed step t-RH before we
      // overwrite ring slot t%RH (its old content is step t-RH).
      if (cons != nullptr && t >= RH) {
        int tgt = t - RH + 1;
        while (true) {
          int f = tgt;
          if (lane < n_cons) f = ld_flag(&cons[lane]);
          if (__all(f >= tgt)) break;
          __builtin_amdgcn_s_sleep(1);
        }
      }
      int pb = lane >> 1, half = lane & 1;
      u64 val = *reinterpret_cast<const u64*>(&hs[pb][half * 4]);
      st_dev(reinterpret_cast<u64*>(hist + ((long)(t & (RH - 1)) * BATCH + pb) * HID + hbase + half * 4), val);
      __asm__ volatile("s_waitcnt vmcnt(0)" ::: "memory");
      if (tid == 0)
        __hip_atomic_store(&fl_own[wg], t + 1, __ATOMIC_RELAXED, __HIP_MEMORY_SCOPE_AGENT);
    }
  }
}

// ---------------- pipelined LayerNorm role (4 WGs x 8 rows) ----------------
__device__ void ln_role(int wg, const u16* __restrict__ in, u16* __restrict__ out,
                        const float* __restrict__ gv, const float* __restrict__ bv,
                        const int* fl_in, int* fl_out, const int* cons)
{
  int tid = threadIdx.x, lane = tid & 63, wave = tid >> 6;
  int row = wg * 8 + wave * 2 + (lane >> 5);
  int l32 = lane & 31, k0 = l32 * 16;
  float gr[16], br[16];
#pragma unroll
  for (int j = 0; j < 16; ++j) { gr[j] = gv[k0 + j]; br[j] = bv[k0 + j]; }

  for (int t = 0; t < T_SEQ; ++t) {
    int tgt = t + 1;
    while (true) {
      int f = ld_flag(&fl_in[lane]);
      if (__all(f >= tgt)) break;
      __builtin_amdgcn_s_sleep(1);
    }
    if (t >= RING) {
      int tg2 = t - RING + 1;
      while (true) {
        int f = ld_flag(&cons[lane]);
        if (__all(f >= tg2)) break;
        __builtin_amdgcn_s_sleep(1);
      }
    }
    __asm__ volatile("" ::: "memory");
    const u16* p = in + ((long)(t & (RING - 1)) * BATCH + row) * HID + k0;
    u32x4 q0, q1;
    GLD16(q0, p, "0");
    GLD16(q1, p, "16");
    asm volatile("s_waitcnt vmcnt(0)" ::: "memory");
    __builtin_amdgcn_sched_barrier(0);
    union { u32x4 q; u16 s[8]; } u0, u1;
    u0.q = q0; u1.q = q1;
    float x[16];
#pragma unroll
    for (int i = 0; i < 8; ++i) { x[i] = bf2f(u0.s[i]); x[8 + i] = bf2f(u1.s[i]); }
    float s = 0.f, s2 = 0.f;
#pragma unroll
    for (int i = 0; i < 16; ++i) { s += x[i]; s2 += x[i] * x[i]; }
#pragma unroll
    for (int off = 1; off < 32; off <<= 1) { s += __shfl_xor(s, off); s2 += __shfl_xor(s2, off); }
    float mu = s * (1.f / 512.f);
    float var = s2 * (1.f / 512.f) - mu * mu;
    float rs = rsqrtf(var + 1e-5f);
    union { u16 o[16]; u32x4 q[2]; } ov;
#pragma unroll
    for (int i = 0; i < 16; ++i) ov.o[i] = f2bf((x[i] - mu) * rs * gr[i] + br[i]);
    u16* po = out + ((long)(t & (RING - 1)) * BATCH + row) * HID + k0;
    GST16(po, ov.q[0], "0");
    GST16(po, ov.q[1], "16");
    asm volatile("s_waitcnt vmcnt(0)" ::: "memory");
    __syncthreads();
    if (tid == 0)
      __hip_atomic_store(&fl_out[wg], t + 1, __ATOMIC_RELAXED, __HIP_MEMORY_SCOPE_AGENT);
  }
}

// ---------------- fused pipeline kernel: 200 WGs ----------------
// flags: [0..63] lstm, [64..67] ln1, [128..191] gru, [192..195] ln2, [256..319] rnn
__global__ __launch_bounds__(256, 1) void fused_kernel(
    const u16* __restrict__ xg, const u16* __restrict__ lstm_whh,
    const u16* __restrict__ gru_wih, const u16* __restrict__ gru_whh,
    const float* __restrict__ gru_bih, const float* __restrict__ gru_bhh,
    const u16* __restrict__ rnn_wih, const u16* __restrict__ rnn_whh,
    const float* __restrict__ rnn_bih, const float* __restrict__ rnn_bhh,
    const float* __restrict__ ln1_g, const float* __restrict__ ln1_b,
    const float* __restrict__ ln2_g, const float* __restrict__ ln2_b,
    u16* h1, u16* ln1o, u16* h2, u16* ln2o, u16* h3, int* fl)
{
  __shared__ u16 w_lds[48][520];     // 49.9 KB  (total static LDS 58.9 KB < 64 KB)
  __shared__ float gx[32][33];       // 4.2 KB
  __shared__ float gh[32][33];       // 4.2 KB
  __shared__ u16 hs[32][8];          // 0.5 KB
  int bid = blockIdx.x;
  if (bid < 64)
    recur_role<0>(bid, xg, nullptr, nullptr, lstm_whh, nullptr, nullptr,
                  h1, nullptr, 0, fl + 0, fl + 64, 4, w_lds, gx, gh, hs);
  else if (bid < 68)
    ln_role(bid - 64, h1, ln1o, ln1_g, ln1_b, fl + 0, fl + 64, fl + 128);
  else if (bid < 132)
    recur_role<1>(bid - 68, nullptr, ln1o, gru_wih, gru_whh, gru_bih, gru_bhh,
                  h2, fl + 64, 4, fl + 128, fl + 192, 4, w_lds, gx, gh, hs);
  else if (bid < 136)
    ln_role(bid - 132, h2, ln2o, ln2_g, ln2_b, fl + 128, fl + 192, fl + 256);
  else
    recur_role<2>(bid - 136, nullptr, ln2o, rnn_wih, rnn_whh, rnn_bih, rnn_bhh,
                  h3, fl + 192, 4, fl + 256, nullptr, 0, w_lds, gx, gh, hs);
}

// ---------------- final FC ----------------
__global__ __launch_bounds__(256) void fc_kernel(
    const u16* __restrict__ hlast, const u16* __restrict__ w,
    const float* __restrict__ bias, float* __restrict__ out)
{
  int tg = blockIdx.x * 256 + threadIdx.x;
  if (tg >= BATCH * 1000) return;
  int b = tg / 1000, o = tg % 1000;
  const u16* hp = hlast + (long)b * HID;
  const u16* wp = w + (long)o * HID;
  float acc = 0.f;
  for (int k = 0; k < HID; k += 8) {
    uint4 hu = *reinterpret_cast<const uint4*>(hp + k);
    uint4 wu = *reinterpret_cast<const uint4*>(wp + k);
    u16* hsv = reinterpret_cast<u16*>(&hu);
    u16* wsv = reinterpret_cast<u16*>(&wu);
#pragma unroll
    for (int i = 0; i < 8; ++i) acc += bf2f(hsv[i]) * bf2f(wsv[i]);
  }
  out[tg] = acc + bias[o];
}

__global__ void sentinel_kernel(float* out) { out[0] = 12345.0f; }

// ---------------- launch ----------------
extern "C" void kernel_launch(void* const* d_in, const int* in_sizes, int n_in,
                              void* d_out, int out_size, void* d_ws, size_t ws_size,
                              hipStream_t stream)
{
  (void)in_sizes; (void)n_in; (void)out_size;
  const float* x        = (const float*)d_in[0];
  const float* lstm_wih = (const float*)d_in[1];
  const float* lstm_whh = (const float*)d_in[2];
  const float* lstm_bih = (const float*)d_in[3];
  const float* lstm_bhh = (const float*)d_in[4];
  const float* ln1_g    = (const float*)d_in[5];
  const float* ln1_b    = (const float*)d_in[6];
  const float* gru_wih  = (const float*)d_in[7];
  const float* gru_whh  = (const float*)d_in[8];
  const float* gru_bih  = (const float*)d_in[9];
  const float* gru_bhh  = (const float*)d_in[10];
  const float* ln2_g    = (const float*)d_in[11];
  const float* ln2_b    = (const float*)d_in[12];
  const float* rnn_wih  = (const float*)d_in[13];
  const float* rnn_whh  = (const float*)d_in[14];
  const float* rnn_bih  = (const float*)d_in[15];
  const float* rnn_bhh  = (const float*)d_in[16];
  const float* fc_w     = (const float*)d_in[17];
  const float* fc_b     = (const float*)d_in[18];
  float* out = (float*)d_out;

  char* ws = (char*)d_ws;
  size_t off = 0;
  auto alloc = [&](size_t bytes) -> void* {
    void* p = ws + off; off += (bytes + 255) & ~(size_t)255; return p;
  };
  int* flags     = (int*)alloc(320 * sizeof(int));
  u16* xbf       = (u16*)alloc((size_t)BATCH * T_SEQ * 256 * 2);
  u16* lstm_wih_b= (u16*)alloc((size_t)2048 * 256 * 2);
  u16* lstm_whh_b= (u16*)alloc((size_t)2048 * 512 * 2);
  u16* gru_wih_b = (u16*)alloc((size_t)1536 * 512 * 2);
  u16* gru_whh_b = (u16*)alloc((size_t)1536 * 512 * 2);
  u16* rnn_wih_b = (u16*)alloc((size_t)512 * 512 * 2);
  u16* rnn_whh_b = (u16*)alloc((size_t)512 * 512 * 2);
  u16* fc_w_b    = (u16*)alloc((size_t)1000 * 512 * 2);
  u16* xg2       = (u16*)alloc((size_t)T_SEQ * BATCH * HID * 4 * 2);  // 128 MB
  u16* h1        = (u16*)alloc((size_t)RING * BATCH * HID * 2);       // 1 MB rings
  u16* ln1o      = (u16*)alloc((size_t)RING * BATCH * HID * 2);
  u16* h2        = (u16*)alloc((size_t)RING * BATCH * HID * 2);
  u16* ln2o      = (u16*)alloc((size_t)RING * BATCH * HID * 2);
  u16* h3        = (u16*)alloc((size_t)2 * BATCH * HID * 2);          // ping-pong

  if (off > ws_size) {
    sentinel_kernel<<<1, 1, 0, stream>>>(out);
    return;
  }

  hipMemsetAsync(flags, 0, 320 * sizeof(int), stream);

  auto cast = [&](const float* src, u16* dst, int n) {
    cast_f32_bf16<<<(n + 2047) / 2048, 256, 0, stream>>>(src, dst, n);
  };
  cast(x,        xbf,        BATCH * T_SEQ * 256);
  cast(lstm_wih, lstm_wih_b, 2048 * 256);
  cast(lstm_whh, lstm_whh_b, 2048 * 512);
  cast(gru_wih,  gru_wih_b,  1536 * 512);
  cast(gru_whh,  gru_whh_b,  1536 * 512);
  cast(rnn_wih,  rnn_wih_b,  512 * 512);
  cast(rnn_whh,  rnn_whh_b,  512 * 512);
  cast(fc_w,     fc_w_b,     1000 * 512);

  const int M64 = (BATCH * T_SEQ) / 64;  // 512
  gemm_xg<<<dim3(M64, 2048 / 64), 256, 0, stream>>>(
      xbf, lstm_wih_b, lstm_bih, lstm_bhh, xg2, 2048, 256, 1024, 1);

  fused_kernel<<<200, 256, 0, stream>>>(
      xg2, lstm_whh_b,
      gru_wih_b, gru_whh_b, gru_bih, gru_bhh,
      rnn_wih_b, rnn_whh_b, rnn_bih, rnn_bhh,
      ln1_g, ln1_b, ln2_g, ln2_b,
      h1, ln1o, h2, ln2o, h3, flags);

  // h3 last written slot = (T_SEQ-1)&1 = 1
  fc_kernel<<<(BATCH * 1000 + 255) / 256, 256, 0, stream>>>(
      h3 + (size_t)BATCH * HID, fc_w_b, fc_b, out);
}

// Round 2
// 6948.849 us; speedup vs baseline: 1.4701x; 1.3380x over previous
//
#include <hip/hip_runtime.h>
#include <stdint.h>

#define T_SEQ 1024
#define BATCH 32
#define HID   512
#define RING  32     // all inter-stage rings: 32 steps deep (power of 2)

typedef unsigned short u16;
typedef unsigned long long u64;
typedef short bf16x8 __attribute__((ext_vector_type(8)));
typedef float f32x4  __attribute__((ext_vector_type(4)));
typedef unsigned int u32x4 __attribute__((ext_vector_type(4)));

// bf16 NaN pattern: unreachable for real ring data (all payloads finite).
#define CAN64 0x7FC07FC07FC07FC0ull

__device__ __forceinline__ float bf2f(u16 u) {
  union { unsigned u; float f; } v; v.u = ((unsigned)u) << 16; return v.f;
}
__device__ __forceinline__ u16 f2bf(float f) {
  union { float f; unsigned u; } v; v.f = f;
  unsigned r = v.u + 0x7fffu + ((v.u >> 16) & 1u);   // RNE
  return (u16)(r >> 16);
}
__device__ __forceinline__ float sigf(float x) { return 1.0f / (1.0f + __expf(-x)); }
__device__ __forceinline__ float tanh_fast(float x) { return 2.0f * sigf(2.0f * x) - 1.0f; }

// Device-scope coherent publish + progress flags.
__device__ __forceinline__ void st_dev(u64* p, u64 v) {
  __hip_atomic_store(p, v, __ATOMIC_RELAXED, __HIP_MEMORY_SCOPE_AGENT);
}
__device__ __forceinline__ int ld_flag(const int* p) {
  return __hip_atomic_load(p, __ATOMIC_RELAXED, __HIP_MEMORY_SCOPE_AGENT);
}

// Coherent 16B load/store: sc0 sc1 bypass L1 + per-XCD L2 (read/write the
// cross-XCD coherence point). Hazard tracking manual (s_waitcnt + sched_barrier).
#define GLD16(dst, p, OFS) \
  asm volatile("global_load_dwordx4 %0, %1, off offset:" OFS " sc0 sc1" \
               : "=v"(dst) : "v"(p) : "memory")
#define GST16(p, val, OFS) \
  asm volatile("global_store_dwordx4 %0, %1, off offset:" OFS " sc0 sc1" \
               :: "v"(p), "v"(val) : "memory")

// 16 named 16B registers (64 VGPRs) so SROA keeps everything in registers.
struct Frag {
  u32x4 d0,d1,d2,d3,d4,d5,d6,d7,d8,d9,d10,d11,d12,d13,d14,d15;
};

__device__ __forceinline__ void issue_frag(const u16* p, Frag& f) {
  GLD16(f.d0,  p, "0");   GLD16(f.d1,  p, "64");
  GLD16(f.d2,  p, "128"); GLD16(f.d3,  p, "192");
  GLD16(f.d4,  p, "256"); GLD16(f.d5,  p, "320");
  GLD16(f.d6,  p, "384"); GLD16(f.d7,  p, "448");
  GLD16(f.d8,  p, "512"); GLD16(f.d9,  p, "576");
  GLD16(f.d10, p, "640"); GLD16(f.d11, p, "704");
  GLD16(f.d12, p, "768"); GLD16(f.d13, p, "832");
  GLD16(f.d14, p, "896"); GLD16(f.d15, p, "960");
}

__device__ __forceinline__ bool chk16(u32x4 q) {
  union { u32x4 q; u64 h[2]; } u; u.q = q;
  return (u.h[0] != CAN64) & (u.h[1] != CAN64);
}
__device__ __forceinline__ bool frag_ok(const Frag& f) {
  bool ok = chk16(f.d0);
  ok &= chk16(f.d1);  ok &= chk16(f.d2);  ok &= chk16(f.d3);
  ok &= chk16(f.d4);  ok &= chk16(f.d5);  ok &= chk16(f.d6);
  ok &= chk16(f.d7);  ok &= chk16(f.d8);  ok &= chk16(f.d9);
  ok &= chk16(f.d10); ok &= chk16(f.d11); ok &= chk16(f.d12);
  ok &= chk16(f.d13); ok &= chk16(f.d14); ok &= chk16(f.d15);
  return ok;
}

// K=512 16x16x32 MFMA chain over a pre-loaded fragment.
__device__ __forceinline__ f32x4 frag_compute(const Frag& f, const u16 (*w)[520],
                                              int wrow, int kq) {
  f32x4 z = {0.f,0.f,0.f,0.f};
  f32x4 a[4] = {z, z, z, z};
#define FSTEP(ii, dd) { union { u32x4 q; bf16x8 v; } c; c.q = f.dd; \
  bf16x8 bv = *reinterpret_cast<const bf16x8*>(&w[wrow][kq + ii * 32]); \
  a[ii & 3] = __builtin_amdgcn_mfma_f32_16x16x32_bf16(c.v, bv, a[ii & 3], 0, 0, 0); }
  FSTEP(0,d0)   FSTEP(1,d1)   FSTEP(2,d2)   FSTEP(3,d3)
  FSTEP(4,d4)   FSTEP(5,d5)   FSTEP(6,d6)   FSTEP(7,d7)
  FSTEP(8,d8)   FSTEP(9,d9)   FSTEP(10,d10) FSTEP(11,d11)
  FSTEP(12,d12) FSTEP(13,d13) FSTEP(14,d14) FSTEP(15,d15)
#undef FSTEP
  return (a[0] + a[1]) + (a[2] + a[3]);
}

// Min of consumer-progress flags across the wave (lanes >= n contribute MAX).
__device__ __forceinline__ int poll_min(const int* base, int n, int lane) {
  int f = 0x7fffffff;
  if (lane < n) f = ld_flag(&base[lane]);
#pragma unroll
  for (int off = 32; off >= 1; off >>= 1) {
    int o = __shfl_xor(f, off);
    f = o < f ? o : f;
  }
  return f;
}

// ---------------- cast fp32 -> bf16 ----------------
__global__ __launch_bounds__(256) void cast_f32_bf16(const float* __restrict__ in,
                                                     u16* __restrict__ out, int n) {
  int i = (blockIdx.x * 256 + threadIdx.x) * 8;
  if (i + 7 < n) {
    float4 v0 = *reinterpret_cast<const float4*>(in + i);
    float4 v1 = *reinterpret_cast<const float4*>(in + i + 4);
    uint4 o;
    o.x = (unsigned)f2bf(v0.x) | ((unsigned)f2bf(v0.y) << 16);
    o.y = (unsigned)f2bf(v0.z) | ((unsigned)f2bf(v0.w) << 16);
    o.z = (unsigned)f2bf(v1.x) | ((unsigned)f2bf(v1.y) << 16);
    o.w = (unsigned)f2bf(v1.z) | ((unsigned)f2bf(v1.w) << 16);
    *reinterpret_cast<uint4*>(out + i) = o;
  } else {
    for (; i < n; ++i) out[i] = f2bf(in[i]);
  }
}

// ---------------- canary fill for the rings ----------------
__global__ __launch_bounds__(256) void fill_canary(u64* __restrict__ p, long n) {
  long i = (long)blockIdx.x * 256 + threadIdx.x;
  if (i < n) p[i] = CAN64;
}

// ---------------- LSTM input GEMM: out[t][b][k][g] = x @ w_ih^T + b_ih + b_hh ----------------
__global__ __launch_bounds__(256) void gemm_xg(
    const u16* __restrict__ A, const u16* __restrict__ W,
    const float* __restrict__ bias1, const float* __restrict__ bias2,
    u16* __restrict__ out, int N, int K, int strideB, int strideT)
{
  __shared__ u16 As[64][72];
  __shared__ u16 Bs[64][72];
  int tid  = threadIdx.x;
  int lane = tid & 63;
  int wave = tid >> 6;
  int m0 = blockIdx.x * 64;
  int n0 = blockIdx.y * 64;

  f32x4 zero = {0.f, 0.f, 0.f, 0.f};
  f32x4 acc[4] = {zero, zero, zero, zero};

  int srow = tid >> 2;
  int scol = (tid & 3) * 16;

  int m_s = m0 + srow;
  long arow = (long)(m_s & (BATCH - 1)) * strideB + (long)(m_s >> 5) * strideT;
  const u16* aptr = A + arow * K + scol;
  const u16* wptr = W + (long)(n0 + srow) * K + scol;

  for (int kk = 0; kk < K; kk += 64) {
    __syncthreads();
    uint4 a0 = *reinterpret_cast<const uint4*>(aptr + kk);
    uint4 a1 = *reinterpret_cast<const uint4*>(aptr + kk + 8);
    uint4 b0 = *reinterpret_cast<const uint4*>(wptr + kk);
    uint4 b1 = *reinterpret_cast<const uint4*>(wptr + kk + 8);
    *reinterpret_cast<uint4*>(&As[srow][scol])     = a0;
    *reinterpret_cast<uint4*>(&As[srow][scol + 8]) = a1;
    *reinterpret_cast<uint4*>(&Bs[srow][scol])     = b0;
    *reinterpret_cast<uint4*>(&Bs[srow][scol + 8]) = b1;
    __syncthreads();
    int am = wave * 16 + (lane & 15);
    int kq = (lane >> 4) * 8;
#pragma unroll
    for (int ks = 0; ks < 2; ++ks) {
      bf16x8 af = *reinterpret_cast<const bf16x8*>(&As[am][kq + ks * 32]);
#pragma unroll
      for (int nb = 0; nb < 4; ++nb) {
        bf16x8 bf = *reinterpret_cast<const bf16x8*>(&Bs[nb * 16 + (lane & 15)][kq + ks * 32]);
        acc[nb] = __builtin_amdgcn_mfma_f32_16x16x32_bf16(af, bf, acc[nb], 0, 0, 0);
      }
    }
  }
  int quad = lane >> 4;
#pragma unroll
  for (int nb = 0; nb < 4; ++nb) {
    int n = n0 + nb * 16 + (lane & 15);
    float bv = bias1[n] + (bias2 ? bias2[n] : 0.0f);
    int g = n >> 9, k = n & 511;
#pragma unroll
    for (int r = 0; r < 4; ++r) {
      int m = m0 + wave * 16 + quad * 4 + r;
      int t = m >> 5, b = m & (BATCH - 1);
      out[(((long)t * BATCH + b) * HID + k) * 4 + g] = f2bf(acc[nb][r] + bv);
    }
  }
}

// ---------------- persistent recurrent role (ROLE: 0=LSTM 1=GRU 2=RNN) ----------------
// Canary protocol: data readiness = payload != canary (no flags on critical path).
// Step t order: [wave0: amortized cons gate + canary slot t+1] -> retry-load
// inputs (vmcnt(0) in loop drains the canary, ordering canary-commit before this
// step's publish) -> MFMA -> cell -> publish (fire-and-forget) -> progress flag.
template <int ROLE>
__device__ void recur_role(
    int wg, const u16* __restrict__ xg, const u16* __restrict__ up,
    const u16* __restrict__ wih, const u16* __restrict__ whh,
    const float* __restrict__ bih, const float* __restrict__ bhh,
    u16* __restrict__ hist, int* fl_own,
    const int* cons, int n_cons,
    u16 (*w_lds)[520], float (*gx)[33], float (*gh)[33], u16 (*hs)[8])
{
  constexpr int NG = (ROLE == 0) ? 4 : (ROLE == 1) ? 3 : 1;
  constexpr int NPAD = (ROLE == 2) ? 16 : 32;
  constexpr int XROWS = (ROLE > 0) ? NG * 8 : 0;   // x-weight rows staged
  constexpr int TOT = XROWS + NG * 8;
  int tid = threadIdx.x, lane = tid & 63, wave = tid >> 6;
  int hbase = wg * 8;

  // stage weights compactly: rows [0,XROWS) = w_ih slice, [XROWS,TOT) = w_hh slice
  for (int idx = tid; idx < TOT * 64; idx += 256) {
    int row = idx >> 6, chunk = idx & 63;
    int n = (row < XROWS) ? row : (row - XROWS);
    const u16* src = (row < XROWS) ? wih : whh;
    int g = n >> 3, dd = n & 7;
    uint4 v = *reinterpret_cast<const uint4*>(src + ((long)(g * 512 + hbase + dd)) * 512 + chunk * 8);
    *reinterpret_cast<uint4*>(&w_lds[row][chunk * 8]) = v;
  }
  __syncthreads();

  int mt = wave & 1, nt = wave >> 1;
  bool mact = (nt * 16) < NPAD;
  int colw = nt * 16 + (lane & 15);
  int wr = (colw < NG * 8) ? colw : (NG * 8 - 1);   // clamped B row (cols>=NG*8 unused)
  int arow = mt * 16 + (lane & 15);
  int kq = (lane >> 4) * 8;
  float bxw = 0.f, bhw = 0.f;
  if (colw < NG * 8) {
    int g = colw >> 3, dd = colw & 7;
    if constexpr (ROLE == 1) { bxw = bih[g * 512 + hbase + dd]; bhw = bhh[g * 512 + hbase + dd]; }
    if constexpr (ROLE == 2) { bxw = bih[hbase + dd] + bhh[hbase + dd]; }
    (void)g;
  }
  int b_c = tid >> 3, d_c = tid & 7;   // cell thread owns h[b_c][hbase+d_c]
  float c_st = 0.f, h_st = 0.f;
  int ccache = 0;                      // cached min of consumer progress

  for (int t = 0; t < T_SEQ; ++t) {
    u64 xq = 0;
    if constexpr (ROLE == 0)
      xq = *reinterpret_cast<const u64*>(xg + (((long)t * BATCH + b_c) * HID + hbase + d_c) * 4);

    f32x4 aX = {0.f,0.f,0.f,0.f}, aH = {0.f,0.f,0.f,0.f};
    if (mact) {
      // --- wave0: gate (amortized) + re-canary slot t+1 of own ring ---
      if (wave == 0) {
        if (cons != nullptr && t >= RING - 1) {
          int need = t - (RING - 2);   // old data step t-31 consumed => cons >= t-30
          while (ccache < need) {
            ccache = poll_min(cons, n_cons, lane);
            if (ccache < need) __builtin_amdgcn_s_sleep(8);
          }
        }
        int pb = lane >> 1, half = lane & 1;
        st_dev(reinterpret_cast<u64*>(
                   hist + (((long)((t + 1) & (RING - 1)) * BATCH + pb) * HID + hbase + half * 4)),
               CAN64);
      }
      // --- retry-load inputs until no canary ---
      Frag fX, fH;
      bool okX = (ROLE == 0), okH = (t == 0);
      const u16* pX = nullptr;
      if constexpr (ROLE > 0)
        pX = up + ((long)(t & (RING - 1)) * BATCH + arow) * HID + kq;
      const u16* pH = hist + ((long)((t - 1) & (RING - 1)) * BATCH + arow) * HID + kq;
      while (!(okX & okH)) {
        if (!okX) issue_frag(pX, fX);
        if (!okH) issue_frag(pH, fH);
        asm volatile("s_waitcnt vmcnt(0)" ::: "memory");
        __builtin_amdgcn_sched_barrier(0);
        if (!okX) okX = (bool)__all(frag_ok(fX));
        if (!okH) okH = (bool)__all(frag_ok(fH));
      }
      if constexpr (ROLE > 0) aX = frag_compute(fX, w_lds, wr, kq);
      if (t > 0)              aH = frag_compute(fH, w_lds + XROWS, wr, kq);

      int quad = lane >> 4;
#pragma unroll
      for (int r = 0; r < 4; ++r) {
        int row = mt * 16 + quad * 4 + r;
        gx[row][colw] = aX[r] + bxw;
        gh[row][colw] = aH[r] + bhw;
      }
    }
    __syncthreads();

    float hnew;
    if constexpr (ROLE == 0) {
      float xv0 = bf2f((u16)(xq));
      float xv1 = bf2f((u16)(xq >> 16));
      float xv2 = bf2f((u16)(xq >> 32));
      float xv3 = bf2f((u16)(xq >> 48));
      float h0 = gh[b_c][0 * 8 + d_c];
      float h1 = gh[b_c][1 * 8 + d_c];
      float h2 = gh[b_c][2 * 8 + d_c];
      float h3 = gh[b_c][3 * 8 + d_c];
      float ig = sigf(xv0 + h0), fg = sigf(xv1 + h1);
      float gg = tanh_fast(xv2 + h2), og = sigf(xv3 + h3);
      c_st = fg * c_st + ig * gg;
      hnew = og * tanh_fast(c_st);
    } else if constexpr (ROLE == 1) {
      float xr_ = gx[b_c][0 * 8 + d_c], xz = gx[b_c][1 * 8 + d_c], xn = gx[b_c][2 * 8 + d_c];
      float hr  = gh[b_c][0 * 8 + d_c], hz = gh[b_c][1 * 8 + d_c], hn = gh[b_c][2 * 8 + d_c];
      float r = sigf(xr_ + hr), z = sigf(xz + hz);
      float n = tanh_fast(xn + r * hn);
      hnew = (1.f - z) * n + z * h_st;
      h_st = hnew;
    } else {
      hnew = tanh_fast(gx[b_c][d_c] + gh[b_c][d_c]);
    }
    hs[b_c][d_c] = f2bf(hnew);
    __syncthreads();

    if (wave == 0) {
      // canary for slot t+1 already drained by the retry loop's vmcnt(0);
      // this vmcnt(0) is a cheap safety net (normally free).
      asm volatile("s_waitcnt vmcnt(0)" ::: "memory");
      int pb = lane >> 1, half = lane & 1;
      u64 val = *reinterpret_cast<const u64*>(&hs[pb][half * 4]);
      st_dev(reinterpret_cast<u64*>(
                 hist + (((long)(t & (RING - 1)) * BATCH + pb) * HID + hbase + half * 4)),
             val);
      if (tid == 0 && fl_own != nullptr)
        __hip_atomic_store(&fl_own[wg], t + 1, __ATOMIC_RELAXED, __HIP_MEMORY_SCOPE_AGENT);
    }
  }
}

// ---------------- pipelined LayerNorm role (4 WGs x 8 rows) ----------------
__device__ void ln_role(int wg, const u16* __restrict__ in, u16* __restrict__ out,
                        const float* __restrict__ gv, const float* __restrict__ bv,
                        int* fl_out, const int* cons, int n_cons)
{
  int tid = threadIdx.x, lane = tid & 63, wave = tid >> 6;
  int row = wg * 8 + wave * 2 + (lane >> 5);
  int l32 = lane & 31, k0 = l32 * 16;
  float gr[16], br[16];
#pragma unroll
  for (int j = 0; j < 16; ++j) { gr[j] = gv[k0 + j]; br[j] = bv[k0 + j]; }
  int ccache = 0;
  u32x4 canv = {0x7FC07FC0u, 0x7FC07FC0u, 0x7FC07FC0u, 0x7FC07FC0u};

  for (int t = 0; t < T_SEQ; ++t) {
    // gate (amortized) + re-canary out slot t+1 (drained by retry vmcnt below)
    if (t >= RING - 1) {
      int need = t - (RING - 2);
      while (ccache < need) {
        ccache = poll_min(cons, n_cons, lane);
        if (ccache < need) __builtin_amdgcn_s_sleep(8);
      }
    }
    u16* pc = out + ((long)((t + 1) & (RING - 1)) * BATCH + row) * HID + k0;
    GST16(pc, canv, "0");
    GST16(pc, canv, "16");

    const u16* p = in + ((long)(t & (RING - 1)) * BATCH + row) * HID + k0;
    u32x4 q0, q1;
    bool ok;
    do {
      GLD16(q0, p, "0");
      GLD16(q1, p, "16");
      asm volatile("s_waitcnt vmcnt(0)" ::: "memory");
      __builtin_amdgcn_sched_barrier(0);
      ok = (bool)__all(chk16(q0) & chk16(q1));
    } while (!ok);

    union { u32x4 q; u16 s[8]; } u0, u1;
    u0.q = q0; u1.q = q1;
    float x[16];
#pragma unroll
    for (int i = 0; i < 8; ++i) { x[i] = bf2f(u0.s[i]); x[8 + i] = bf2f(u1.s[i]); }
    float s = 0.f, s2 = 0.f;
#pragma unroll
    for (int i = 0; i < 16; ++i) { s += x[i]; s2 += x[i] * x[i]; }
#pragma unroll
    for (int off = 1; off < 32; off <<= 1) { s += __shfl_xor(s, off); s2 += __shfl_xor(s2, off); }
    float mu = s * (1.f / 512.f);
    float var = s2 * (1.f / 512.f) - mu * mu;
    float rs = rsqrtf(var + 1e-5f);
    union { u16 o[16]; u32x4 q[2]; } ov;
#pragma unroll
    for (int i = 0; i < 16; ++i) ov.o[i] = f2bf((x[i] - mu) * rs * gr[i] + br[i]);
    u16* po = out + ((long)(t & (RING - 1)) * BATCH + row) * HID + k0;
    GST16(po, ov.q[0], "0");
    GST16(po, ov.q[1], "16");
    __syncthreads();
    if (tid == 0)
      __hip_atomic_store(&fl_out[wg], t + 1, __ATOMIC_RELAXED, __HIP_MEMORY_SCOPE_AGENT);
  }
}

// ---------------- fused pipeline kernel: 200 WGs ----------------
// progress flags (back-pressure only): [64..67] ln1, [128..191] gru,
// [192..195] ln2, [256..319] rnn
__global__ __launch_bounds__(256, 1) void fused_kernel(
    const u16* __restrict__ xg, const u16* __restrict__ lstm_whh,
    const u16* __restrict__ gru_wih, const u16* __restrict__ gru_whh,
    const float* __restrict__ gru_bih, const float* __restrict__ gru_bhh,
    const u16* __restrict__ rnn_wih, const u16* __restrict__ rnn_whh,
    const float* __restrict__ rnn_bih, const float* __restrict__ rnn_bhh,
    const float* __restrict__ ln1_g, const float* __restrict__ ln1_b,
    const float* __restrict__ ln2_g, const float* __restrict__ ln2_b,
    u16* h1, u16* ln1o, u16* h2, u16* ln2o, u16* h3, int* fl)
{
  __shared__ u16 w_lds[48][520];     // 49.9 KB  (total static LDS 58.9 KB < 64 KB)
  __shared__ float gx[32][33];       // 4.2 KB
  __shared__ float gh[32][33];       // 4.2 KB
  __shared__ u16 hs[32][8];          // 0.5 KB
  int bid = blockIdx.x;
  if (bid < 64)
    recur_role<0>(bid, xg, nullptr, nullptr, lstm_whh, nullptr, nullptr,
                  h1, nullptr, fl + 64, 4, w_lds, gx, gh, hs);
  else if (bid < 68)
    ln_role(bid - 64, h1, ln1o, ln1_g, ln1_b, fl + 64, fl + 128, 64);
  else if (bid < 132)
    recur_role<1>(bid - 68, nullptr, ln1o, gru_wih, gru_whh, gru_bih, gru_bhh,
                  h2, fl + 128, fl + 192, 4, w_lds, gx, gh, hs);
  else if (bid < 136)
    ln_role(bid - 132, h2, ln2o, ln2_g, ln2_b, fl + 192, fl + 256, 64);
  else
    recur_role<2>(bid - 136, nullptr, ln2o, rnn_wih, rnn_whh, rnn_bih, rnn_bhh,
                  h3, fl + 256, nullptr, 0, w_lds, gx, gh, hs);
}

// ---------------- final FC ----------------
__global__ __launch_bounds__(256) void fc_kernel(
    const u16* __restrict__ hlast, const u16* __restrict__ w,
    const float* __restrict__ bias, float* __restrict__ out)
{
  int tg = blockIdx.x * 256 + threadIdx.x;
  if (tg >= BATCH * 1000) return;
  int b = tg / 1000, o = tg % 1000;
  const u16* hp = hlast + (long)b * HID;
  const u16* wp = w + (long)o * HID;
  float acc = 0.f;
  for (int k = 0; k < HID; k += 8) {
    uint4 hu = *reinterpret_cast<const uint4*>(hp + k);
    uint4 wu = *reinterpret_cast<const uint4*>(wp + k);
    u16* hsv = reinterpret_cast<u16*>(&hu);
    u16* wsv = reinterpret_cast<u16*>(&wu);
#pragma unroll
    for (int i = 0; i < 8; ++i) acc += bf2f(hsv[i]) * bf2f(wsv[i]);
  }
  out[tg] = acc + bias[o];
}

__global__ void sentinel_kernel(float* out) { out[0] = 12345.0f; }

// ---------------- launch ----------------
extern "C" void kernel_launch(void* const* d_in, const int* in_sizes, int n_in,
                              void* d_out, int out_size, void* d_ws, size_t ws_size,
                              hipStream_t stream)
{
  (void)in_sizes; (void)n_in; (void)out_size;
  const float* x        = (const float*)d_in[0];
  const float* lstm_wih = (const float*)d_in[1];
  const float* lstm_whh = (const float*)d_in[2];
  const float* lstm_bih = (const float*)d_in[3];
  const float* lstm_bhh = (const float*)d_in[4];
  const float* ln1_g    = (const float*)d_in[5];
  const float* ln1_b    = (const float*)d_in[6];
  const float* gru_wih  = (const float*)d_in[7];
  const float* gru_whh  = (const float*)d_in[8];
  const float* gru_bih  = (const float*)d_in[9];
  const float* gru_bhh  = (const float*)d_in[10];
  const float* ln2_g    = (const float*)d_in[11];
  const float* ln2_b    = (const float*)d_in[12];
  const float* rnn_wih  = (const float*)d_in[13];
  const float* rnn_whh  = (const float*)d_in[14];
  const float* rnn_bih  = (const float*)d_in[15];
  const float* rnn_bhh  = (const float*)d_in[16];
  const float* fc_w     = (const float*)d_in[17];
  const float* fc_b     = (const float*)d_in[18];
  float* out = (float*)d_out;

  char* ws = (char*)d_ws;
  size_t off = 0;
  auto alloc = [&](size_t bytes) -> void* {
    void* p = ws + off; off += (bytes + 255) & ~(size_t)255; return p;
  };
  int* flags     = (int*)alloc(320 * sizeof(int));
  u16* xbf       = (u16*)alloc((size_t)BATCH * T_SEQ * 256 * 2);
  u16* lstm_wih_b= (u16*)alloc((size_t)2048 * 256 * 2);
  u16* lstm_whh_b= (u16*)alloc((size_t)2048 * 512 * 2);
  u16* gru_wih_b = (u16*)alloc((size_t)1536 * 512 * 2);
  u16* gru_whh_b = (u16*)alloc((size_t)1536 * 512 * 2);
  u16* rnn_wih_b = (u16*)alloc((size_t)512 * 512 * 2);
  u16* rnn_whh_b = (u16*)alloc((size_t)512 * 512 * 2);
  u16* fc_w_b    = (u16*)alloc((size_t)1000 * 512 * 2);
  u16* xg2       = (u16*)alloc((size_t)T_SEQ * BATCH * HID * 4 * 2);  // 128 MB
  // 5 contiguous 1 MB rings (each size % 256 == 0 -> no padding between)
  u16* h1        = (u16*)alloc((size_t)RING * BATCH * HID * 2);
  u16* ln1o      = (u16*)alloc((size_t)RING * BATCH * HID * 2);
  u16* h2        = (u16*)alloc((size_t)RING * BATCH * HID * 2);
  u16* ln2o      = (u16*)alloc((size_t)RING * BATCH * HID * 2);
  u16* h3        = (u16*)alloc((size_t)RING * BATCH * HID * 2);

  if (off > ws_size) {
    sentinel_kernel<<<1, 1, 0, stream>>>(out);
    return;
  }

  hipMemsetAsync(flags, 0, 320 * sizeof(int), stream);

  // pre-fill all rings with the canary pattern
  const long ncan = 5L * RING * BATCH * HID * 2 / 8;   // u64 count over 5 rings
  fill_canary<<<(int)((ncan + 255) / 256), 256, 0, stream>>>((u64*)h1, ncan);

  auto cast = [&](const float* src, u16* dst, int n) {
    cast_f32_bf16<<<(n + 2047) / 2048, 256, 0, stream>>>(src, dst, n);
  };
  cast(x,        xbf,        BATCH * T_SEQ * 256);
  cast(lstm_wih, lstm_wih_b, 2048 * 256);
  cast(lstm_whh, lstm_whh_b, 2048 * 512);
  cast(gru_wih,  gru_wih_b,  1536 * 512);
  cast(gru_whh,  gru_whh_b,  1536 * 512);
  cast(rnn_wih,  rnn_wih_b,  512 * 512);
  cast(rnn_whh,  rnn_whh_b,  512 * 512);
  cast(fc_w,     fc_w_b,     1000 * 512);

  const int M64 = (BATCH * T_SEQ) / 64;  // 512
  gemm_xg<<<dim3(M64, 2048 / 64), 256, 0, stream>>>(
      xbf, lstm_wih_b, lstm_bih, lstm_bhh, xg2, 2048, 256, 1024, 1);

  fused_kernel<<<200, 256, 0, stream>>>(
      xg2, lstm_whh_b,
      gru_wih_b, gru_whh_b, gru_bih, gru_bhh,
      rnn_wih_b, rnn_whh_b, rnn_bih, rnn_bhh,
      ln1_g, ln1_b, ln2_g, ln2_b,
      h1, ln1o, h2, ln2o, h3, flags);

  // h3 last written slot = (T_SEQ-1)&31 = 31
  fc_kernel<<<(BATCH * 1000 + 255) / 256, 256, 0, stream>>>(
      h3 + (size_t)31 * BATCH * HID, fc_w_b, fc_b, out);
}